// Round 1
// baseline (576.011 us; speedup 1.0000x reference)
//
#include <hip/hip_runtime.h>
#include <math.h>

#define Nn   64
#define NCL_ 128
#define NCc  512
#define REPr 2048
#define Dd   512

__device__ __forceinline__ float swishf(float x) { return x * (1.0f / (1.0f + __expf(-x))); }

// ---- K1: fused RepNorm invariant norms + BatchNorm1d. Block per channel (512),
// thread per batch element (64 = one wave). Batch stats via shuffle reduce. ----
__global__ void k_normbn(const float* __restrict__ x1d, float* __restrict__ norm,
                         float* __restrict__ nb, float* __restrict__ a2) {
    int c = blockIdx.x;              // 512 blocks = one channel each
    int n = threadIdx.x;             // 64 threads = one node each (exactly 1 wave)
    int l = c >> 7;
    int ch = c & 127;
    int nm = 2 * l + 1;
    const float* base = x1d + n * REPr + l * l * 128 + ch;
    float s = 0.f;
    for (int m = 0; m < nm; m++) { float v = base[m * 128]; s += v * v; }
    float nv = sqrtf(s);
    // batch statistics across the wave (N = 64 = wave size)
    float s1 = nv, s2 = nv * nv;
    for (int m = 1; m < 64; m <<= 1) {
        s1 += __shfl_xor(s1, m, 64);
        s2 += __shfl_xor(s2, m, 64);
    }
    float mu  = s1 * (1.0f / Nn);
    float var = s2 * (1.0f / Nn) - mu * mu;
    float inv = rsqrtf(var + 1e-5f);
    norm[n * NCc + c] = nv;
    nb[n * NCc + c]   = (nv - mu) * inv;
    if (c < 4) a2[c * 64 + n] = 0.f;   // zero gate accumulator (ws is poisoned)
}

// ---- K2: transpose Wie[l][o][i] -> WieT[l][i][o] so k_ielin reads coalesced ----
__global__ void k_twie(const float* __restrict__ Wie, float* __restrict__ WieT) {
    __shared__ float t[32][33];
    int l  = blockIdx.x >> 4;        // 4 l's x 16 tiles = 64 blocks
    int tb = blockIdx.x & 15;
    int ro = (tb >> 2) * 32;         // o-tile origin
    int ci = (tb & 3) * 32;          // i-tile origin
    int tx = threadIdx.x & 31, ty = threadIdx.x >> 5;   // 256 threads = 32x8
    const float* src = Wie  + l * 16384;
    float*       dst = WieT + l * 16384;
#pragma unroll
    for (int k = 0; k < 32; k += 8)
        t[ty + k][tx] = src[(ro + ty + k) * 128 + ci + tx];
    __syncthreads();
#pragma unroll
    for (int k = 0; k < 32; k += 8)
        dst[(ci + ty + k) * 128 + ro + tx] = t[tx][ty + k];
}

// ---- K3: dense layer out[n,j] = act(in[n,:]·W[j,:] + b[j]); wave per (n, 8 j's).
// float4 loads: lane covers indices [lane*8, lane*8+8) -> 32B/lane coalesced. ----
__global__ void k_dense(const float* __restrict__ in, const float* __restrict__ W,
                        const float* __restrict__ b, float* __restrict__ out, int act) {
    int wave = blockIdx.x * 4 + (threadIdx.x >> 6);   // 4096 waves total
    int lane = threadIdx.x & 63;
    int n = wave >> 6;
    int j0 = (wave & 63) * 8;
    const float4* in4 = (const float4*)(in + n * NCc);
    float4 xa = in4[lane * 2];
    float4 xb = in4[lane * 2 + 1];
#pragma unroll
    for (int jj = 0; jj < 8; jj++) {
        int j = j0 + jj;
        const float4* row = (const float4*)(W + j * NCc);
        float4 wa = row[lane * 2];
        float4 wb = row[lane * 2 + 1];
        float acc = xa.x * wa.x + xa.y * wa.y + xa.z * wa.z + xa.w * wa.w
                  + xb.x * wb.x + xb.y * wb.y + xb.z * wb.z + xb.w * wb.w;
        for (int m = 1; m < 64; m <<= 1) acc += __shfl_xor(acc, m, 64);
        if (lane == 0) {
            float y = acc + b[j];
            out[n * NCc + j] = act ? swishf(y) : y;
        }
    }
}

// ---- K4: gauge + IELin + scalar_mul -> x1d_new (output 0). Uses transposed WieT
// so the inner-loop weight load is lane-coalesced (was a 64-line gather). ----
__global__ void k_ielin(const float* __restrict__ x1d, const float* __restrict__ norm,
                        const float* __restrict__ n2, const float* __restrict__ WieT,
                        float* __restrict__ out) {
    __shared__ float gv[NCL_];
    int bid = blockIdx.x;            // n*16 + lm
    int n = bid >> 4;
    int lm = bid & 15;
    int l = (lm >= 9) ? 3 : ((lm >= 4) ? 2 : ((lm >= 1) ? 1 : 0));
    int off = lm * 128;              // rep offset of this (l,m) block
    int coff = l * 128;              // channel offset
    int t = threadIdx.x;             // 128 threads
    gv[t] = x1d[n * REPr + off + t] / (norm[n * NCc + coff + t] + 1e-2f);
    __syncthreads();
    const float* w = WieT + l * NCL_ * NCL_;   // WieT[l][i][o]
    float acc = 0.f;
#pragma unroll 8
    for (int i = 0; i < NCL_; i++) acc += gv[i] * w[i * NCL_ + t];
    out[n * REPr + off + t] = acc * n2[n * NCc + coff + t];
}

// ---- K5: a2[n,c] = sum_p f[n,p,c] * (sum_q x2d[n,p,q,c] * f[n,q,c]) ----
// n0: node-group offset (L3-locality batching with k_out2d)
__global__ void k_bilinear(const float* __restrict__ x2d, const float* __restrict__ f,
                           float* __restrict__ a2, int n0) {
    __shared__ float4 fbuf[Dd];
    __shared__ float cont[4][4];
    int bid = blockIdx.x;            // (n-n0)*128 + pg
    int n = n0 + (bid >> 7);
    int pg = bid & 127;
    int tid = threadIdx.x;           // 256
    const float4* f4 = (const float4*)(f + n * REPr);
    fbuf[tid] = f4[tid];
    fbuf[tid + 256] = f4[tid + 256];
    __syncthreads();
    int w = tid >> 6, lane = tid & 63;
    int p = pg * 4 + w;
    const float4* x4 = (const float4*)x2d + (size_t)(n * Dd + p) * Dd;
    float4 acc = {0.f, 0.f, 0.f, 0.f};
    for (int q = lane; q < Dd; q += 64) {
        float4 xv = x4[q];
        float4 fv = fbuf[q];
        acc.x += xv.x * fv.x; acc.y += xv.y * fv.y;
        acc.z += xv.z * fv.z; acc.w += xv.w * fv.w;
    }
    for (int m = 1; m < 64; m <<= 1) {
        acc.x += __shfl_xor(acc.x, m, 64);
        acc.y += __shfl_xor(acc.y, m, 64);
        acc.z += __shfl_xor(acc.z, m, 64);
        acc.w += __shfl_xor(acc.w, m, 64);
    }
    if (lane == 0) {
        float4 fp = fbuf[p];
        cont[w][0] = acc.x * fp.x; cont[w][1] = acc.y * fp.y;
        cont[w][2] = acc.z * fp.z; cont[w][3] = acc.w * fp.w;
    }
    __syncthreads();
    if (tid < 4) {
        float s = cont[0][tid] + cont[1][tid] + cont[2][tid] + cont[3][tid];
        atomicAdd(&a2[n * 4 + tid], s);
    }
}

// ---- K6: x2d_new[n,p,q,d] = (sum_c x2d[n,p,q,c]*Wt[d,c]) * swish(a2[n,:]·Wg[d,:]+bg[d]) ----
__global__ void k_out2d(const float* __restrict__ x2d, const float* __restrict__ a2,
                        const float* __restrict__ Wt, const float* __restrict__ Wg,
                        const float* __restrict__ bg, float* __restrict__ out, int n0) {
    int bid = blockIdx.x;            // (n-n0)*64 + chunk
    int n = n0 + (bid >> 6);
    int chunk = bid & 63;
    float a[4], gate[4], sw[16];
#pragma unroll
    for (int c = 0; c < 4; c++) a[c] = a2[n * 4 + c];
#pragma unroll
    for (int d = 0; d < 4; d++) {
        float y = bg[d];
#pragma unroll
        for (int c = 0; c < 4; c++) y += Wg[d * 4 + c] * a[c];
        gate[d] = swishf(y);
    }
#pragma unroll
    for (int d = 0; d < 4; d++)
#pragma unroll
        for (int c = 0; c < 4; c++) sw[d * 4 + c] = Wt[d * 4 + c] * gate[d];
    const float4* in4 = (const float4*)x2d;
    float4* out4 = (float4*)out;
    size_t base = (size_t)n * (Dd * Dd) + (size_t)chunk * 4096 + threadIdx.x;
#pragma unroll
    for (int i = 0; i < 16; i++) {
        size_t e = base + (size_t)i * 256;
        float4 x = in4[e];
        float4 y;
        y.x = sw[0] * x.x + sw[1] * x.y + sw[2] * x.z + sw[3] * x.w;
        y.y = sw[4] * x.x + sw[5] * x.y + sw[6] * x.z + sw[7] * x.w;
        y.z = sw[8] * x.x + sw[9] * x.y + sw[10] * x.z + sw[11] * x.w;
        y.w = sw[12] * x.x + sw[13] * x.y + sw[14] * x.z + sw[15] * x.w;
        out4[e] = y;
    }
}

extern "C" void kernel_launch(void* const* d_in, const int* in_sizes, int n_in,
                              void* d_out, int out_size, void* d_ws, size_t ws_size,
                              hipStream_t stream) {
    const float* x1d = (const float*)d_in[0];
    const float* x2d = (const float*)d_in[1];
    const float* W1  = (const float*)d_in[2];
    const float* b1  = (const float*)d_in[3];
    const float* W2  = (const float*)d_in[4];
    const float* b2  = (const float*)d_in[5];
    const float* Wie = (const float*)d_in[6];
    const float* Wt  = (const float*)d_in[7];
    const float* Wg  = (const float*)d_in[8];
    const float* bg  = (const float*)d_in[9];

    float* out1d = (float*)d_out;                       // [64, 2048]
    float* out2d = out1d + (size_t)Nn * REPr;           // [64, 512, 512, 4]

    float* ws   = (float*)d_ws;
    float* norm = ws;                   // 32768
    float* nb   = ws + 32768;           // 32768
    float* h    = ws + 65536;           // 32768
    float* n2   = ws + 98304;           // 32768
    float* a2   = ws + 131072;          // 256
    float* WieT = ws + 131328;          // 65536 (4 x 128 x 128 transposed Wie)

    k_normbn<<<NCc, 64, 0, stream>>>(x1d, norm, nb, a2);
    k_twie<<<64, 256, 0, stream>>>(Wie, WieT);
    k_dense<<<1024, 256, 0, stream>>>(nb, W1, b1, h, 1);
    k_dense<<<1024, 256, 0, stream>>>(h, W2, b2, n2, 0);
    k_ielin<<<Nn * 16, NCL_, 0, stream>>>(x1d, norm, n2, WieT, out1d);
    // L3-locality batching: process nodes in groups of 8 so k_out2d's re-read of
    // x2d (4 MB/node) hits the 256 MB L3 instead of HBM (group working set 32 MB).
    for (int g = 0; g < 8; g++) {
        k_bilinear<<<8 * 128, 256, 0, stream>>>(x2d, out1d, a2, g * 8);
        k_out2d<<<8 * 64, 256, 0, stream>>>(x2d, a2, Wt, Wg, bg, out2d, g * 8);
    }
}

// Round 2
// 529.240 us; speedup vs baseline: 1.0884x; 1.0884x over previous
//
#include <hip/hip_runtime.h>
#include <math.h>

#define Nn   64
#define NCL_ 128
#define NCc  512
#define REPr 2048
#define Dd   512

__device__ __forceinline__ float swishf(float x) { return x * (1.0f / (1.0f + __expf(-x))); }

// ---- K1: fused RepNorm invariant norms + BatchNorm1d. Block per channel (512),
// thread per batch element (64 = one wave). Batch stats via shuffle reduce. ----
__global__ void k_normbn(const float* __restrict__ x1d, float* __restrict__ norm,
                         float* __restrict__ nb, float* __restrict__ a2) {
    int c = blockIdx.x;              // 512 blocks = one channel each
    int n = threadIdx.x;             // 64 threads = one node each (exactly 1 wave)
    int l = c >> 7;
    int ch = c & 127;
    int nm = 2 * l + 1;
    const float* base = x1d + n * REPr + l * l * 128 + ch;
    float s = 0.f;
    for (int m = 0; m < nm; m++) { float v = base[m * 128]; s += v * v; }
    float nv = sqrtf(s);
    // batch statistics across the wave (N = 64 = wave size)
    float s1 = nv, s2 = nv * nv;
    for (int m = 1; m < 64; m <<= 1) {
        s1 += __shfl_xor(s1, m, 64);
        s2 += __shfl_xor(s2, m, 64);
    }
    float mu  = s1 * (1.0f / Nn);
    float var = s2 * (1.0f / Nn) - mu * mu;
    float inv = rsqrtf(var + 1e-5f);
    norm[n * NCc + c] = nv;
    nb[n * NCc + c]   = (nv - mu) * inv;
    if (c < 4) a2[c * 64 + n] = 0.f;   // zero gate accumulator (ws is poisoned)
}

// ---- K2: transpose Wie[l][o][i] -> WieT[l][i][o] so k_ielin reads coalesced ----
__global__ void k_twie(const float* __restrict__ Wie, float* __restrict__ WieT) {
    __shared__ float t[32][33];
    int l  = blockIdx.x >> 4;        // 4 l's x 16 tiles = 64 blocks
    int tb = blockIdx.x & 15;
    int ro = (tb >> 2) * 32;         // o-tile origin
    int ci = (tb & 3) * 32;          // i-tile origin
    int tx = threadIdx.x & 31, ty = threadIdx.x >> 5;   // 256 threads = 32x8
    const float* src = Wie  + l * 16384;
    float*       dst = WieT + l * 16384;
#pragma unroll
    for (int k = 0; k < 32; k += 8)
        t[ty + k][tx] = src[(ro + ty + k) * 128 + ci + tx];
    __syncthreads();
#pragma unroll
    for (int k = 0; k < 32; k += 8)
        dst[(ci + ty + k) * 128 + ro + tx] = t[tx][ty + k];
}

// ---- K3: dense layer out[n,j] = act(in[n,:]·W[j,:] + b[j]); wave per (n, 8 j's).
// float4 loads: lane covers indices [lane*8, lane*8+8) -> 32B/lane coalesced. ----
__global__ void k_dense(const float* __restrict__ in, const float* __restrict__ W,
                        const float* __restrict__ b, float* __restrict__ out, int act) {
    int wave = blockIdx.x * 4 + (threadIdx.x >> 6);   // 4096 waves total
    int lane = threadIdx.x & 63;
    int n = wave >> 6;
    int j0 = (wave & 63) * 8;
    const float4* in4 = (const float4*)(in + n * NCc);
    float4 xa = in4[lane * 2];
    float4 xb = in4[lane * 2 + 1];
#pragma unroll
    for (int jj = 0; jj < 8; jj++) {
        int j = j0 + jj;
        const float4* row = (const float4*)(W + j * NCc);
        float4 wa = row[lane * 2];
        float4 wb = row[lane * 2 + 1];
        float acc = xa.x * wa.x + xa.y * wa.y + xa.z * wa.z + xa.w * wa.w
                  + xb.x * wb.x + xb.y * wb.y + xb.z * wb.z + xb.w * wb.w;
        for (int m = 1; m < 64; m <<= 1) acc += __shfl_xor(acc, m, 64);
        if (lane == 0) {
            float y = acc + b[j];
            out[n * NCc + j] = act ? swishf(y) : y;
        }
    }
}

// ---- K4: gauge + IELin + scalar_mul -> x1d_new (output 0). Uses transposed WieT
// so the inner-loop weight load is lane-coalesced (was a 64-line gather). ----
__global__ void k_ielin(const float* __restrict__ x1d, const float* __restrict__ norm,
                        const float* __restrict__ n2, const float* __restrict__ WieT,
                        float* __restrict__ out) {
    __shared__ float gv[NCL_];
    int bid = blockIdx.x;            // n*16 + lm
    int n = bid >> 4;
    int lm = bid & 15;
    int l = (lm >= 9) ? 3 : ((lm >= 4) ? 2 : ((lm >= 1) ? 1 : 0));
    int off = lm * 128;              // rep offset of this (l,m) block
    int coff = l * 128;              // channel offset
    int t = threadIdx.x;             // 128 threads
    gv[t] = x1d[n * REPr + off + t] / (norm[n * NCc + coff + t] + 1e-2f);
    __syncthreads();
    const float* w = WieT + l * NCL_ * NCL_;   // WieT[l][i][o]
    float acc = 0.f;
#pragma unroll 8
    for (int i = 0; i < NCL_; i++) acc += gv[i] * w[i * NCL_ + t];
    out[n * REPr + off + t] = acc * n2[n * NCc + coff + t];
}

// ---- K5: a2[n,c] = sum_p f[n,p,c] * (sum_q x2d[n,p,q,c] * f[n,q,c]) ----
// n0: node-group offset (L3-locality batching with k_out2d)
__global__ void k_bilinear(const float* __restrict__ x2d, const float* __restrict__ f,
                           float* __restrict__ a2, int n0) {
    __shared__ float4 fbuf[Dd];
    __shared__ float cont[4][4];
    int bid = blockIdx.x;            // (n-n0)*128 + pg
    int n = n0 + (bid >> 7);
    int pg = bid & 127;
    int tid = threadIdx.x;           // 256
    const float4* f4 = (const float4*)(f + n * REPr);
    fbuf[tid] = f4[tid];
    fbuf[tid + 256] = f4[tid + 256];
    __syncthreads();
    int w = tid >> 6, lane = tid & 63;
    int p = pg * 4 + w;
    const float4* x4 = (const float4*)x2d + (size_t)(n * Dd + p) * Dd;
    float4 acc = {0.f, 0.f, 0.f, 0.f};
    for (int q = lane; q < Dd; q += 64) {
        float4 xv = x4[q];
        float4 fv = fbuf[q];
        acc.x += xv.x * fv.x; acc.y += xv.y * fv.y;
        acc.z += xv.z * fv.z; acc.w += xv.w * fv.w;
    }
    for (int m = 1; m < 64; m <<= 1) {
        acc.x += __shfl_xor(acc.x, m, 64);
        acc.y += __shfl_xor(acc.y, m, 64);
        acc.z += __shfl_xor(acc.z, m, 64);
        acc.w += __shfl_xor(acc.w, m, 64);
    }
    if (lane == 0) {
        float4 fp = fbuf[p];
        cont[w][0] = acc.x * fp.x; cont[w][1] = acc.y * fp.y;
        cont[w][2] = acc.z * fp.z; cont[w][3] = acc.w * fp.w;
    }
    __syncthreads();
    if (tid < 4) {
        float s = cont[0][tid] + cont[1][tid] + cont[2][tid] + cont[3][tid];
        atomicAdd(&a2[n * 4 + tid], s);
    }
}

// ---- K6: x2d_new[n,p,q,d] = (sum_c x2d[n,p,q,c]*Wt[d,c]) * swish(a2[n,:]·Wg[d,:]+bg[d]) ----
__global__ void k_out2d(const float* __restrict__ x2d, const float* __restrict__ a2,
                        const float* __restrict__ Wt, const float* __restrict__ Wg,
                        const float* __restrict__ bg, float* __restrict__ out, int n0) {
    int bid = blockIdx.x;            // (n-n0)*64 + chunk
    int n = n0 + (bid >> 6);
    int chunk = bid & 63;
    float a[4], gate[4], sw[16];
#pragma unroll
    for (int c = 0; c < 4; c++) a[c] = a2[n * 4 + c];
#pragma unroll
    for (int d = 0; d < 4; d++) {
        float y = bg[d];
#pragma unroll
        for (int c = 0; c < 4; c++) y += Wg[d * 4 + c] * a[c];
        gate[d] = swishf(y);
    }
#pragma unroll
    for (int d = 0; d < 4; d++)
#pragma unroll
        for (int c = 0; c < 4; c++) sw[d * 4 + c] = Wt[d * 4 + c] * gate[d];
    const float4* in4 = (const float4*)x2d;
    float4* out4 = (float4*)out;
    size_t base = (size_t)n * (Dd * Dd) + (size_t)chunk * 4096 + threadIdx.x;
#pragma unroll
    for (int i = 0; i < 16; i++) {
        size_t e = base + (size_t)i * 256;
        float4 x = in4[e];
        float4 y;
        y.x = sw[0] * x.x + sw[1] * x.y + sw[2] * x.z + sw[3] * x.w;
        y.y = sw[4] * x.x + sw[5] * x.y + sw[6] * x.z + sw[7] * x.w;
        y.z = sw[8] * x.x + sw[9] * x.y + sw[10] * x.z + sw[11] * x.w;
        y.w = sw[12] * x.x + sw[13] * x.y + sw[14] * x.z + sw[15] * x.w;
        out4[e] = y;
    }
}

extern "C" void kernel_launch(void* const* d_in, const int* in_sizes, int n_in,
                              void* d_out, int out_size, void* d_ws, size_t ws_size,
                              hipStream_t stream) {
    const float* x1d = (const float*)d_in[0];
    const float* x2d = (const float*)d_in[1];
    const float* W1  = (const float*)d_in[2];
    const float* b1  = (const float*)d_in[3];
    const float* W2  = (const float*)d_in[4];
    const float* b2  = (const float*)d_in[5];
    const float* Wie = (const float*)d_in[6];
    const float* Wt  = (const float*)d_in[7];
    const float* Wg  = (const float*)d_in[8];
    const float* bg  = (const float*)d_in[9];

    float* out1d = (float*)d_out;                       // [64, 2048]
    float* out2d = out1d + (size_t)Nn * REPr;           // [64, 512, 512, 4]

    float* ws   = (float*)d_ws;
    float* norm = ws;                   // 32768
    float* nb   = ws + 32768;           // 32768
    float* h    = ws + 65536;           // 32768
    float* n2   = ws + 98304;           // 32768
    float* a2   = ws + 131072;          // 256
    float* WieT = ws + 131328;          // 65536 (4 x 128 x 128 transposed Wie)

    k_normbn<<<NCc, 64, 0, stream>>>(x1d, norm, nb, a2);
    k_twie<<<64, 256, 0, stream>>>(Wie, WieT);
    k_dense<<<1024, 256, 0, stream>>>(nb, W1, b1, h, 1);
    k_dense<<<1024, 256, 0, stream>>>(h, W2, b2, n2, 0);
    k_ielin<<<Nn * 16, NCL_, 0, stream>>>(x1d, norm, n2, WieT, out1d);
    // L3-locality batching: 2 groups of 32 nodes. Group working set = 32 x 4 MB
    // = 128 MB << 256 MB L3, so k_out2d's re-read of x2d hits Infinity Cache.
    // Grids stay large (4096 / 2048 blocks) so BW stays saturated; only 2 extra
    // launches vs the ungrouped version (the 8-group variant regressed on gaps).
    for (int g = 0; g < 2; g++) {
        k_bilinear<<<32 * 128, 256, 0, stream>>>(x2d, out1d, a2, g * 32);
        k_out2d<<<32 * 64, 256, 0, stream>>>(x2d, a2, Wt, Wg, bg, out2d, g * 32);
    }
}